// Round 10
// baseline (259.309 us; speedup 1.0000x reference)
//
#include <hip/hip_runtime.h>
#include <math.h>

#define NB 4
#define NN 4096
#define KSEL 204
#define NBINS 512
#define CANDN 256
#define QKSCALE 0.31622776601683794f

// workspace layout in floats
#define WS_Q 0
#define WS_KT (NB * NN * 10)       // 163840
#define WS_V (2 * NB * NN * 10)    // 327680
#define WS_LG (3 * NB * NN * 10)   // 491520  (+ NB*NN*2 = 32768)

#define SEQ_PER_BLOCK 16

typedef float v2f __attribute__((ext_vector_type(2)));

// kT layout: [B][10][N] row-major (the [B][N/64][10][64] variant broke L2
// write-combining of out_probs -> 14x WRITE_SIZE; keep row-major).
// attn structure: R0's 4-waves-per-row. R4 (2 rows/blk, Occ 43%) and R7
// (1 wave/row, Occ 22%) both LOST despite less VALU work: duration tracks
// occupancy. Only occupancy-preserving trims allowed here.

__global__ __launch_bounds__(256) void featqkv_kernel(
    const float* __restrict__ x,
    const float* __restrict__ w2, const float* __restrict__ b2,
    const float* __restrict__ w3, const float* __restrict__ b3,
    const float* __restrict__ w4, const float* __restrict__ b4,
    const float* __restrict__ w5, const float* __restrict__ b5,
    const float* __restrict__ w6, const float* __restrict__ b6,
    const float* __restrict__ w7, const float* __restrict__ b7,
    const float* __restrict__ wq, const float* __restrict__ bq,
    const float* __restrict__ wk, const float* __restrict__ bk,
    const float* __restrict__ wv, const float* __restrict__ bv,
    float* __restrict__ q_out, float* __restrict__ kT_out, float* __restrict__ v_out)
{
    __shared__ __align__(16) float xs[SEQ_PER_BLOCK * 360];
    __shared__ float wpad[14 * 105];   // zero-padded to 7 taps: [ch][c=15][j=7]
    __shared__ float bconv[14];
    __shared__ float wqkv[420];
    __shared__ float bqkv[30];
    __shared__ float feats[SEQ_PER_BLOCK * 14];

    const int t = threadIdx.x;
    const int g0 = blockIdx.x * SEQ_PER_BLOCK;

    // ---- stage x as float4 ----
    {
        const float4* xg4 = reinterpret_cast<const float4*>(x + (size_t)g0 * 360);
        float4* xs4 = reinterpret_cast<float4*>(xs);
        for (int i = t; i < SEQ_PER_BLOCK * 90; i += 256) xs4[i] = xg4[i];
    }

    // ---- stage conv weights, zero-padded to uniform 7 taps ----
    for (int i = t; i < 14 * 105; i += 256) {
        const int ch = i / 105;
        const int r = i - ch * 105;
        const int c = r / 7;
        const int j = r - (r / 7) * 7;
        float val = 0.f;
        if (ch < 3)       { if (j < 2) val = w2[ch * 30 + c * 2 + j]; }
        else if (ch < 6)  { if (j < 3) val = w3[(ch - 3) * 45 + c * 3 + j]; }
        else if (ch < 9)  { if (j < 4) val = w4[(ch - 6) * 60 + c * 4 + j]; }
        else if (ch < 11) { if (j < 5) val = w5[(ch - 9) * 75 + c * 5 + j]; }
        else if (ch < 13) { if (j < 6) val = w6[(ch - 11) * 90 + c * 6 + j]; }
        else              { val = w7[c * 7 + j]; }
        wpad[i] = val;
    }
    if (t < 3) bconv[t] = b2[t];
    else if (t < 6) bconv[t] = b3[t - 3];
    else if (t < 9) bconv[t] = b4[t - 6];
    else if (t < 11) bconv[t] = b5[t - 9];
    else if (t < 13) bconv[t] = b6[t - 11];
    else if (t == 13) bconv[t] = b7[0];
    for (int i = t; i < 140; i += 256) wqkv[i] = wq[i];
    for (int i = t; i < 140; i += 256) wqkv[140 + i] = wk[i];
    for (int i = t; i < 140; i += 256) wqkv[280 + i] = wv[i];
    if (t < 10) bqkv[t] = bq[t];
    else if (t < 20) bqkv[t] = bk[t - 10];
    else if (t < 30) bqkv[t] = bv[t - 20];
    __syncthreads();

    const int seq = t >> 4;
    const int wkr = t & 15;

    if (wkr < 14) {
        const int ch = wkr;
        int T;
        if (ch < 3) T = 23; else if (ch < 6) T = 22; else if (ch < 9) T = 21;
        else if (ch < 11) T = 20; else if (ch < 13) T = 19; else T = 18;

        float acc[23];
#pragma unroll
        for (int u = 0; u < 23; u++) acc[u] = 0.f;
        const float* xrow = &xs[seq * 360];
        const float* wrow = &wpad[ch * 105];
        for (int c = 0; c < 15; c++) {
            float xr[30];
            const float4* xp = reinterpret_cast<const float4*>(xrow + c * 24);
#pragma unroll
            for (int u4 = 0; u4 < 6; u4++) {
                const float4 xv = xp[u4];
                xr[u4 * 4 + 0] = xv.x; xr[u4 * 4 + 1] = xv.y;
                xr[u4 * 4 + 2] = xv.z; xr[u4 * 4 + 3] = xv.w;
            }
#pragma unroll
            for (int u = 24; u < 30; u++) xr[u] = 0.f;
#pragma unroll
            for (int j = 0; j < 7; j++) {
                const float wv_ = wrow[c * 7 + j];
#pragma unroll
                for (int tt = 0; tt < 23; tt++)
                    acc[tt] = fmaf(xr[tt + j], wv_, acc[tt]);
            }
        }
        float m = -3.0e38f;
#pragma unroll
        for (int tt = 0; tt < 23; tt++)
            if (tt < T) m = fmaxf(m, acc[tt]);
        feats[seq * 14 + ch] = fmaxf(m + bconv[ch], 0.f);
    }
    __syncthreads();

    const int g = g0 + seq;
    const int b_ = g >> 12;
    const int n_ = g & 4095;
    for (int o = wkr; o < 30; o += 16) {
        const int type = o / 10;
        const int comp = o % 10;
        const float* wrow = &wqkv[type * 140 + comp * 14];
        const float* frow = &feats[seq * 14];
        float a = bqkv[type * 10 + comp];
#pragma unroll
        for (int ii = 0; ii < 14; ii++) a = fmaf(frow[ii], wrow[ii], a);
        if (type == 0) q_out[(size_t)g * 10 + comp] = a;
        else if (type == 1) kT_out[((size_t)b_ * 10 + comp) * NN + n_] = a;
        else v_out[(size_t)g * 10 + comp] = a;
    }
}

__device__ __forceinline__ float dec_key(unsigned int k) {
    return (k & 0x80000000u) ? __uint_as_float(k ^ 0x80000000u)
                             : __uint_as_float(~k);
}
__device__ __forceinline__ unsigned int enc_key(float s) {
    unsigned int u = __float_as_uint(s);
    return (u & 0x80000000u) ? ~u : (u | 0x80000000u);
}

// 256 threads / 1 row per block (R0 structure). Scores in registers;
// linear-histogram rank. Packed-f32 FMA in P1; merged P6/P7 barrier;
// P8 wave0-only (6 barriers total vs 8).
__global__ __launch_bounds__(256, 8) void attn_kernel(
    const float* __restrict__ qbuf, const float* __restrict__ kTbuf,
    const float* __restrict__ vbuf,
    const float* __restrict__ w_attn, const float* __restrict__ b_attn,
    const float* __restrict__ w_mil, const float* __restrict__ b_mil,
    float* __restrict__ out_probs, float* __restrict__ logits)
{
    __shared__ unsigned int base_[NBINS];   // counts -> suffix-above (pristine)
    __shared__ unsigned int bc_[NBINS];     // mutable scatter counters
    __shared__ unsigned long long cand[CANDN];
    __shared__ float hpart[4], lpart[4], fpart[4];
    __shared__ unsigned int wtot[4];
    __shared__ float ctxp[40];

    const int t = threadIdx.x;
    const int lane = t & 63;
    const int w = t >> 6;
    const int row = blockIdx.x;
    const int b_ = row >> 12;

    // ---- P1: scores (registers, packed f32 FMA) + block min/max ----
    float q0, q1, q2, q3, q4, q5, q6, q7, q8, q9;
    {
        const float* qp = qbuf + (size_t)row * 10;
        q0 = qp[0]; q1 = qp[1]; q2 = qp[2]; q3 = qp[3]; q4 = qp[4];
        q5 = qp[5]; q6 = qp[6]; q7 = qp[7]; q8 = qp[8]; q9 = qp[9];
    }
    const float* kTb = kTbuf + (size_t)b_ * 10 * NN;
    float sc[16];
    float vhi = -1e30f, vlo = 1e30f;
#pragma unroll
    for (int i = 0; i < 4; i++) {
        v2f a01 = {0.f, 0.f};
        v2f a23 = {0.f, 0.f};
#pragma unroll
        for (int c = 0; c < 10; c++) {
            const float qc = (c == 0) ? q0 : (c == 1) ? q1 : (c == 2) ? q2 : (c == 3) ? q3 :
                             (c == 4) ? q4 : (c == 5) ? q5 : (c == 6) ? q6 : (c == 7) ? q7 :
                             (c == 8) ? q8 : q9;
            const float4 kv = reinterpret_cast<const float4*>(kTb + c * NN)[i * 256 + t];
            v2f kxy; kxy.x = kv.x; kxy.y = kv.y;
            v2f kzw; kzw.x = kv.z; kzw.y = kv.w;
            v2f qv; qv.x = qc; qv.y = qc;
            a01 = __builtin_elementwise_fma(qv, kxy, a01);
            a23 = __builtin_elementwise_fma(qv, kzw, a23);
        }
        sc[i * 4 + 0] = a01.x; sc[i * 4 + 1] = a01.y;
        sc[i * 4 + 2] = a23.x; sc[i * 4 + 3] = a23.y;
        vhi = fmaxf(vhi, fmaxf(fmaxf(a01.x, a01.y), fmaxf(a23.x, a23.y)));
        vlo = fminf(vlo, fminf(fminf(a01.x, a01.y), fminf(a23.x, a23.y)));
    }
#pragma unroll
    for (int off = 32; off > 0; off >>= 1) {
        vhi = fmaxf(vhi, __shfl_xor(vhi, off));
        vlo = fminf(vlo, __shfl_xor(vlo, off));
    }
    if (lane == 0) { hpart[w] = vhi; lpart[w] = vlo; }
    // zero hist + cand under same barrier
    base_[2 * t] = 0u; base_[2 * t + 1] = 0u;
    cand[t] = 0ULL;
    __syncthreads();                                            // B1
    const float hi = fmaxf(fmaxf(hpart[0], hpart[1]), fmaxf(hpart[2], hpart[3]));
    const float lo = fminf(fminf(lpart[0], lpart[1]), fminf(lpart[2], lpart[3]));
    const bool degen = (hi <= lo);

    float pv = 0.f;
    int jj = 0, p = KSEL;
    bool selected = false;
    const float smax = hi * QKSCALE;

    if (!degen) {
        const float scale = (float)(NBINS - 1) / (hi - lo);

        // ---- P2: 512-bin linear histogram (bins cached in registers) ----
        int bins[16];
#pragma unroll
        for (int i = 0; i < 16; i++) {
            const int bin = (int)fminf((sc[i] - lo) * scale, (float)(NBINS - 1));
            bins[i] = bin;
            atomicAdd(&base_[bin], 1u);
        }
        __syncthreads();                                        // B2

        // ---- P3: suffix scan (2 bins/thread) -> base (pristine) + bc (mutable) ----
        {
            const unsigned int c0 = base_[2 * t];
            const unsigned int c1 = base_[2 * t + 1];
            const unsigned int T_ = c0 + c1;
            unsigned int acc = T_;
#pragma unroll
            for (int off = 1; off < 64; off <<= 1) {
                unsigned int o = __shfl_down(acc, off);
                if (lane + off < 64) acc += o;
            }
            if (lane == 0) wtot[w] = acc;
            __syncthreads();                                    // B3
            unsigned int tail = 0u;
#pragma unroll
            for (int w2 = 1; w2 < 4; w2++) if (w2 > w) tail += wtot[w2];
            const unsigned int A = (acc - T_) + tail;   // keys in bins > 2t+1
            base_[2 * t + 1] = A;
            base_[2 * t] = A + c1;
            bc_[2 * t + 1] = A;
            bc_[2 * t] = A + c1;
        }
        __syncthreads();                                        // B4

        // ---- P4: scatter candidate keys (bins whose base < KSEL) ----
#pragma unroll
        for (int i = 0; i < 16; i++) {
            const int bin = bins[i];
            const unsigned int bs = base_[bin];
            if (bs < KSEL) {
                const unsigned int pos = atomicAdd(&bc_[bin], 1u);
                if (pos < CANDN) {
                    const int j = (i >> 2) * 1024 + t * 4 + (i & 3);
                    cand[pos] = (((unsigned long long)enc_key(sc[i])) << 16)
                              | (unsigned long long)(4095 - j);
                }
            }
        }
        __syncthreads();                                        // B5

        // ---- P5: within-bin rank -> exact sorted position ----
        const unsigned long long mine = cand[t];
        if (mine != 0ULL) {
            const float s = dec_key((unsigned int)(mine >> 16));
            const int bin = (int)fminf((s - lo) * scale, (float)(NBINS - 1));
            const unsigned int bs = base_[bin];
            // bin's keys occupy [base[bin], base[bin-1])
            unsigned int e2 = (bin > 0) ? base_[bin - 1] : 4096u;
            if (e2 > CANDN) e2 = CANDN;
            unsigned int rank = 0;
            for (unsigned int s2 = bs; s2 < e2; s2++)
                rank += (cand[s2] > mine) ? 1u : 0u;
            const unsigned int pp = bs + rank;
            if (pp < KSEL) {
                selected = true;
                p = (int)pp;
                jj = 4095 - (int)(mine & 0xFFFFu);
                pv = expf(s * QKSCALE - smax);
            }
        }
    } else {
        // all scores equal: top-K = lowest indices, uniform softmax
        if (t < KSEL) {
            selected = true;
            p = t;
            jj = t;
            pv = 1.f;
        }
    }

    // ---- P6+P7 merged: UNNORMALIZED ctx + denom in ONE butterfly round ----
    float cx0 = 0.f, cx1 = 0.f, cx2 = 0.f, cx3 = 0.f, cx4 = 0.f;
    float cx5 = 0.f, cx6 = 0.f, cx7 = 0.f, cx8 = 0.f, cx9 = 0.f;
    if (selected) {
        const float* vr = vbuf + ((size_t)b_ * NN + (size_t)jj) * 10;
        const float2 v01 = reinterpret_cast<const float2*>(vr)[0];
        const float2 v23 = reinterpret_cast<const float2*>(vr)[1];
        const float2 v45 = reinterpret_cast<const float2*>(vr)[2];
        const float2 v67 = reinterpret_cast<const float2*>(vr)[3];
        const float2 v89 = reinterpret_cast<const float2*>(vr)[4];
        cx0 = pv * v01.x; cx1 = pv * v01.y;
        cx2 = pv * v23.x; cx3 = pv * v23.y;
        cx4 = pv * v45.x; cx5 = pv * v45.y;
        cx6 = pv * v67.x; cx7 = pv * v67.y;
        cx8 = pv * v89.x; cx9 = pv * v89.y;
    }
    float dsum = pv;
#pragma unroll
    for (int off = 32; off > 0; off >>= 1) {
        dsum += __shfl_xor(dsum, off);
        cx0 += __shfl_xor(cx0, off); cx1 += __shfl_xor(cx1, off);
        cx2 += __shfl_xor(cx2, off); cx3 += __shfl_xor(cx3, off);
        cx4 += __shfl_xor(cx4, off); cx5 += __shfl_xor(cx5, off);
        cx6 += __shfl_xor(cx6, off); cx7 += __shfl_xor(cx7, off);
        cx8 += __shfl_xor(cx8, off); cx9 += __shfl_xor(cx9, off);
    }
    if (lane == 0) {
        fpart[w] = dsum;
        ctxp[w * 10 + 0] = cx0; ctxp[w * 10 + 1] = cx1; ctxp[w * 10 + 2] = cx2;
        ctxp[w * 10 + 3] = cx3; ctxp[w * 10 + 4] = cx4; ctxp[w * 10 + 5] = cx5;
        ctxp[w * 10 + 6] = cx6; ctxp[w * 10 + 7] = cx7; ctxp[w * 10 + 8] = cx8;
        ctxp[w * 10 + 9] = cx9;
    }
    __syncthreads();                                            // B6 (last)
    const float inv = 1.f / (fpart[0] + fpart[1] + fpart[2] + fpart[3]);

    // probs out (normalized now that inv is known)
    if (selected) out_probs[(size_t)row * KSEL + p] = pv * inv;

    // ---- P8: attn projection + mil logits, wave 0 only (no more barriers) ----
    if (w == 0) {
        float m0 = 0.f, m1 = 0.f;
        if (lane < 14) {
            float a = b_attn[lane];
#pragma unroll
            for (int d = 0; d < 10; d++) {
                const float ctxd = (ctxp[d] + ctxp[10 + d] + ctxp[20 + d] + ctxp[30 + d]) * inv;
                a = fmaf(ctxd, w_attn[lane * 10 + d], a);
            }
            m0 = a * w_mil[lane];
            m1 = a * w_mil[14 + lane];
        }
#pragma unroll
        for (int off = 8; off > 0; off >>= 1) {
            m0 += __shfl_xor(m0, off);
            m1 += __shfl_xor(m1, off);
        }
        if (lane == 0) {
            float2 lgv;
            lgv.x = m0 + b_mil[0];
            lgv.y = m1 + b_mil[1];
            *reinterpret_cast<float2*>(logits + (size_t)row * 2) = lgv;
        }
    }
}

__global__ __launch_bounds__(256) void pool_kernel(
    const float* __restrict__ logits, float* __restrict__ out)
{
    __shared__ float red[256];
    const int t = threadIdx.x;
    const int bc = blockIdx.x;
    const int b_ = bc >> 1;
    const int c_ = bc & 1;
    float a = 0.f;
    for (int n2 = t; n2 < NN; n2 += 256)
        a += logits[((size_t)b_ * NN + n2) * 2 + c_];
    red[t] = a;
    __syncthreads();
    for (int off = 128; off > 0; off >>= 1) {
        if (t < off) red[t] += red[t + off];
        __syncthreads();
    }
    if (t == 0) out[bc] = red[0] * (1.f / 4096.f);
}

extern "C" void kernel_launch(void* const* d_in, const int* in_sizes, int n_in,
                              void* d_out, int out_size, void* d_ws, size_t ws_size,
                              hipStream_t stream) {
    const float* x  = (const float*)d_in[0];
    const float* w2 = (const float*)d_in[1];  const float* b2 = (const float*)d_in[2];
    const float* w3 = (const float*)d_in[3];  const float* b3 = (const float*)d_in[4];
    const float* w4 = (const float*)d_in[5];  const float* b4 = (const float*)d_in[6];
    const float* w5 = (const float*)d_in[7];  const float* b5 = (const float*)d_in[8];
    const float* w6 = (const float*)d_in[9];  const float* b6 = (const float*)d_in[10];
    const float* w7 = (const float*)d_in[11]; const float* b7 = (const float*)d_in[12];
    const float* wq = (const float*)d_in[13]; const float* bq = (const float*)d_in[14];
    const float* wk = (const float*)d_in[15]; const float* bk = (const float*)d_in[16];
    const float* wv = (const float*)d_in[17]; const float* bv = (const float*)d_in[18];
    const float* wat = (const float*)d_in[19]; const float* bat = (const float*)d_in[20];
    const float* wm = (const float*)d_in[21];  const float* bm = (const float*)d_in[22];

    float* ws = (float*)d_ws;
    float* qb = ws + WS_Q;
    float* kT = ws + WS_KT;
    float* vb = ws + WS_V;
    float* lg = ws + WS_LG;
    float* out = (float*)d_out;

    hipLaunchKernelGGL(featqkv_kernel, dim3(NB * NN / SEQ_PER_BLOCK), dim3(256), 0, stream,
                       x, w2, b2, w3, b3, w4, b4, w5, b5, w6, b6, w7, b7,
                       wq, bq, wk, bk, wv, bv, qb, kT, vb);
    hipLaunchKernelGGL(attn_kernel, dim3(NB * NN), dim3(256), 0, stream,
                       qb, kT, vb, wat, bat, wm, bm, out + 8, lg);
    hipLaunchKernelGGL(pool_kernel, dim3(8), dim3(256), 0, stream, lg, out);
}